// Round 1
// baseline (11908.295 us; speedup 1.0000x reference)
//
#include <hip/hip_runtime.h>
#include <math.h>

#define NDIS 8192
#define NMIR 16384
#define DIMD 256
#define BPAIR 65536
#define KSEL 50
#define EPSF 1e-8f

// knn GEMM tiling
#define RB 64    // rows per workgroup
#define CB 128   // cols per tile
#define KS 64    // k-slice
#define AST 68   // A LDS row stride (floats)
#define BST 68   // B LDS row stride
#define SST 132  // sims LDS row stride

__device__ __forceinline__ float wredsum(float v) {
#pragma unroll
  for (int off = 1; off < 64; off <<= 1) v += __shfl_xor(v, off, 64);
  return v;
}

__device__ __forceinline__ float softplusf(float x) {
  return fmaxf(x, 0.0f) + log1pf(expf(-fabsf(x)));
}

__device__ __forceinline__ float dot4f(const float4 a, const float4 b) {
  return a.x * b.x + a.y * b.y + a.z * b.z + a.w * b.w;
}

// ---------- Kernel A: pair scores + contrastive loss partials ----------
__global__ __launch_bounds__(256) void pair_kernel(
    const float* __restrict__ h, const float* __restrict__ srci,
    const float* __restrict__ dsti, const int* __restrict__ dis,
    const int* __restrict__ mir, float* __restrict__ scores,
    float* __restrict__ pairpart) {
  const int lane = threadIdx.x & 63;
  const int widx = threadIdx.x >> 6;
  const int gw = blockIdx.x * 4 + widx;  // 4096 waves total
  float lsum = 0.0f;
  for (int b = gw; b < BPAIR; b += 4096) {
    const int d = dis[b];
    const int m = mir[b];
    const float4 a4 = ((const float4*)(h + (size_t)d * DIMD))[lane];
    const float4 m4 = ((const float4*)(h + (size_t)m * DIMD))[lane];
    const float4 s4 = ((const float4*)(srci + (size_t)b * DIMD))[lane];
    const float4 t4 = ((const float4*)(dsti + (size_t)b * DIMD))[lane];
    float aa = dot4f(a4, a4);
    float ss = dot4f(s4, s4);
    float tt = dot4f(t4, t4);
    float as = dot4f(a4, s4);
    float at = dot4f(a4, t4);
    float am = dot4f(a4, m4);
    aa = wredsum(aa); ss = wredsum(ss); tt = wredsum(tt);
    as = wredsum(as); at = wredsum(at); am = wredsum(am);
    const float ra = fmaxf(sqrtf(aa), EPSF);
    const float pos = as / (ra * fmaxf(sqrtf(ss), EPSF));
    const float neg = at / (ra * fmaxf(sqrtf(tt), EPSF));
    lsum += softplusf(neg - pos);
    if (lane == 0) scores[b] = 1.0f / (1.0f + expf(-am));
  }
  __shared__ float wsum[4];
  if (lane == 0) wsum[widx] = lsum;
  __syncthreads();
  if (threadIdx.x == 0)
    pairpart[blockIdx.x] = (wsum[0] + wsum[1]) + (wsum[2] + wsum[3]);
}

// ---------- Kernel B: fused sim-GEMM + top-50 + neighbor average ----------
// 256 threads = 4 waves. C-tile: 64 rows x 128 cols, thread tile 8x4
// (rows interleaved: r = i*8+tr, cols c = j*32+tc for bank-conflict-free b128).
__global__ __launch_bounds__(256) void knn_kernel(
    const float* __restrict__ feat, const int N, float* __restrict__ upd) {
  __shared__ float As[RB * AST];  // 17408 B
  __shared__ float Bs[CB * BST];  // 34816 B (reused for sims 64x132)
  float* Ss = Bs;

  const int tid = threadIdx.x;
  const int lane = tid & 63;
  const int widx = tid >> 6;
  const int tr = tid & 7;
  const int tc = tid >> 3;  // 0..31
  const int rowbase = blockIdx.x * RB;

  // per-wave top-50 lists: lane k holds slot k (k<50), others +inf dummies
  float tv[16];
  int ti[16];
  float thr[16];
#pragma unroll
  for (int q = 0; q < 16; ++q) {
    tv[q] = (lane < KSEL) ? -3.4e38f : 3.4e38f;
    ti[q] = 0;
    thr[q] = -3.4e38f;
  }

  for (int cb = 0; cb < N; cb += CB) {
    float acc[8][4];
#pragma unroll
    for (int i = 0; i < 8; ++i)
#pragma unroll
      for (int j = 0; j < 4; ++j) acc[i][j] = 0.0f;

    for (int ks = 0; ks < DIMD; ks += KS) {
      __syncthreads();  // protect LDS reuse (prev compute / prev sims)
      // stage A slice: 64 rows x 64 k
#pragma unroll
      for (int it = 0; it < 4; ++it) {
        const int f = tid + 256 * it;
        const int r = f >> 4, kq = f & 15;
        *(float4*)&As[r * AST + kq * 4] =
            *(const float4*)&feat[(size_t)(rowbase + r) * DIMD + ks + kq * 4];
      }
      // stage B slice: 128 cols x 64 k
#pragma unroll
      for (int it = 0; it < 8; ++it) {
        const int f = tid + 256 * it;
        const int c = f >> 4, kq = f & 15;
        *(float4*)&Bs[c * BST + kq * 4] =
            *(const float4*)&feat[(size_t)(cb + c) * DIMD + ks + kq * 4];
      }
      __syncthreads();
#pragma unroll 4
      for (int kk = 0; kk < KS; kk += 4) {
        float4 av[8], bv[4];
#pragma unroll
        for (int i = 0; i < 8; ++i)
          av[i] = *(const float4*)&As[(i * 8 + tr) * AST + kk];
#pragma unroll
        for (int j = 0; j < 4; ++j)
          bv[j] = *(const float4*)&Bs[(j * 32 + tc) * BST + kk];
#pragma unroll
        for (int i = 0; i < 8; ++i)
#pragma unroll
          for (int j = 0; j < 4; ++j) acc[i][j] += dot4f(av[i], bv[j]);
      }
    }
    __syncthreads();  // all waves done reading Bs -> reuse as sims
#pragma unroll
    for (int i = 0; i < 8; ++i)
#pragma unroll
      for (int j = 0; j < 4; ++j)
        Ss[(i * 8 + tr) * SST + (j * 32 + tc)] = acc[i][j];
    __syncthreads();

    // selection: wave widx owns rows widx*16..+15
#pragma unroll
    for (int q = 0; q < 16; ++q) {
      const int r = (widx << 4) + q;
      const int grow = rowbase + r;
#pragma unroll
      for (int half = 0; half < 2; ++half) {
        const int cc = (half << 6) + lane;
        const float v = Ss[r * SST + cc];
        const int gc = cb + cc;
        unsigned long long mask = __ballot((gc != grow) && (v > thr[q]));
        while (mask) {
          const int src = (int)__builtin_ctzll(mask);
          mask &= (mask - 1);
          const float cv = __shfl(v, src, 64);
          if (cv > thr[q]) {  // cheap conservative pre-filter (uniform)
            // argmin over the 50 slots (uniform result on all lanes)
            float mv = tv[q];
            int ml = lane;
#pragma unroll
            for (int off = 1; off < 64; off <<= 1) {
              const float ov = __shfl_xor(mv, off, 64);
              const int ol = __shfl_xor(ml, off, 64);
              if (ov < mv || (ov == mv && ol < ml)) { mv = ov; ml = ol; }
            }
            if (cv > mv && lane == ml) {
              tv[q] = cv;
              ti[q] = cb + (half << 6) + src;
            }
            thr[q] = mv;  // true min before replacement: conservative
          }
        }
      }
    }
  }

  // gather the 50 neighbors and average
#pragma unroll
  for (int q = 0; q < 16; ++q) {
    const int r = (widx << 4) + q;
    const int grow = rowbase + r;
    float ax = 0.f, ay = 0.f, az = 0.f, aw = 0.f;
    for (int t = 0; t < KSEL; ++t) {
      const int j = __shfl(ti[q], t, 64);
      const float4 f4 = ((const float4*)(feat + (size_t)j * DIMD))[lane];
      ax += f4.x; ay += f4.y; az += f4.z; aw += f4.w;
    }
    const float inv = 1.0f / (float)KSEL;
    float4 o;
    o.x = ax * inv; o.y = ay * inv; o.z = az * inv; o.w = aw * inv;
    ((float4*)(upd + (size_t)grow * DIMD))[lane] = o;
  }
}

// ---------- Kernel C1: per-column partial sums for center ----------
__global__ __launch_bounds__(256) void center_partial(
    const float* __restrict__ upd, const int N, float* __restrict__ part) {
  const int c = threadIdx.x;
  const int rows_per = N >> 7;  // grid = 128 blocks
  const int r0 = blockIdx.x * rows_per;
  float s = 0.0f;
  for (int i = 0; i < rows_per; ++i) s += upd[(size_t)(r0 + i) * DIMD + c];
  part[blockIdx.x * DIMD + c] = s;
}

// ---------- Kernel C2: finalize center + its norm ----------
__global__ __launch_bounds__(256) void center_final(
    const float* __restrict__ part, const int N, float* __restrict__ center,
    float* __restrict__ cnorm) {
  const int c = threadIdx.x;
  float s = 0.0f;
  for (int b = 0; b < 128; ++b) s += part[b * DIMD + c];
  s /= (float)N;
  center[c] = s;
  __shared__ float red[256];
  red[c] = s * s;
  __syncthreads();
  for (int off = 128; off > 0; off >>= 1) {
    if (c < off) red[c] += red[c + off];
    __syncthreads();
  }
  if (c == 0) cnorm[0] = sqrtf(red[0]);
}

// ---------- Kernel D: per-row cos vs both centers + softplus partials ----
__global__ __launch_bounds__(256) void knn_loss(
    const float* __restrict__ upd, const int N,
    const float* __restrict__ centers, const float* __restrict__ cnorms,
    const int group, float* __restrict__ part) {
  const int lane = threadIdx.x & 63;
  const int widx = threadIdx.x >> 6;
  const int gw = blockIdx.x * 4 + widx;  // 1024 waves
  const float4 ca = ((const float4*)centers)[lane];
  const float4 cbv = ((const float4*)(centers + DIMD))[lane];
  const float na = fmaxf(cnorms[0], EPSF);
  const float nb = fmaxf(cnorms[1], EPSF);
  float lsum = 0.0f;
  for (int r = gw; r < N; r += 1024) {
    const float4 u = ((const float4*)(upd + (size_t)r * DIMD))[lane];
    float uu = dot4f(u, u);
    float uca = dot4f(u, ca);
    float ucb = dot4f(u, cbv);
    uu = wredsum(uu); uca = wredsum(uca); ucb = wredsum(ucb);
    const float nu = fmaxf(sqrtf(uu), EPSF);
    const float sa = uca / (nu * na);
    const float sb = ucb / (nu * nb);
    const float x = (group == 0) ? (sb - sa) : (sa - sb);
    lsum += softplusf(x);
  }
  __shared__ float wsum[4];
  if (lane == 0) wsum[widx] = lsum;
  __syncthreads();
  if (threadIdx.x == 0)
    part[blockIdx.x] = (wsum[0] + wsum[1]) + (wsum[2] + wsum[3]);
}

// ---------- Kernel E: final scalar reductions ----------
__global__ __launch_bounds__(256) void finalize_kernel(
    const float* __restrict__ pairpart, const float* __restrict__ lpa,
    const float* __restrict__ lpb, float* __restrict__ out) {
  __shared__ float red[256];
  const int t = threadIdx.x;

  float s = 0.0f;
  for (int i = t; i < 1024; i += 256) s += pairpart[i];
  red[t] = s;
  __syncthreads();
  for (int off = 128; off > 0; off >>= 1) {
    if (t < off) red[t] += red[t + off];
    __syncthreads();
  }
  const float pairsum = red[0];
  __syncthreads();

  red[t] = lpa[t];
  __syncthreads();
  for (int off = 128; off > 0; off >>= 1) {
    if (t < off) red[t] += red[t + off];
    __syncthreads();
  }
  const float la = red[0];
  __syncthreads();

  red[t] = lpb[t];
  __syncthreads();
  for (int off = 128; off > 0; off >>= 1) {
    if (t < off) red[t] += red[t + off];
    __syncthreads();
  }
  const float lb = red[0];

  if (t == 0) {
    out[BPAIR] = pairsum / (float)BPAIR;
    out[BPAIR + 1] = 0.5f * (la / (float)NDIS + lb / (float)NMIR);
  }
}

extern "C" void kernel_launch(void* const* d_in, const int* in_sizes, int n_in,
                              void* d_out, int out_size, void* d_ws,
                              size_t ws_size, hipStream_t stream) {
  const float* h = (const float*)d_in[0];
  const float* emb = (const float*)d_in[1];
  const float* srci = (const float*)d_in[2];
  const float* dsti = (const float*)d_in[3];
  const int* dis = (const int*)d_in[4];
  const int* mir = (const int*)d_in[5];
  float* out = (float*)d_out;

  float* W = (float*)d_ws;
  float* upd_d = W;                        // 8192*256
  float* upd_m = upd_d + (size_t)NDIS * DIMD;  // 16384*256
  float* pairpart = upd_m + (size_t)NMIR * DIMD;  // 1024
  float* cpart_d = pairpart + 1024;        // 128*256
  float* cpart_m = cpart_d + 32768;        // 128*256
  float* centers = cpart_m + 32768;        // 512 (d then m)
  float* cnorms = centers + 512;           // 2 (pad 64)
  float* lpa = cnorms + 64;                // 256
  float* lpb = lpa + 256;                  // 256

  pair_kernel<<<1024, 256, 0, stream>>>(h, srci, dsti, dis, mir, out, pairpart);
  knn_kernel<<<NDIS / RB, 256, 0, stream>>>(emb, NDIS, upd_d);
  knn_kernel<<<NMIR / RB, 256, 0, stream>>>(emb + (size_t)NDIS * DIMD, NMIR,
                                            upd_m);
  center_partial<<<128, 256, 0, stream>>>(upd_d, NDIS, cpart_d);
  center_partial<<<128, 256, 0, stream>>>(upd_m, NMIR, cpart_m);
  center_final<<<1, 256, 0, stream>>>(cpart_d, NDIS, centers, cnorms);
  center_final<<<1, 256, 0, stream>>>(cpart_m, NMIR, centers + DIMD,
                                      cnorms + 1);
  knn_loss<<<256, 256, 0, stream>>>(upd_d, NDIS, centers, cnorms, 0, lpa);
  knn_loss<<<256, 256, 0, stream>>>(upd_m, NMIR, centers, cnorms, 1, lpb);
  finalize_kernel<<<1, 256, 0, stream>>>(pairpart, lpa, lpb, out);
}

// Round 2
// 4654.722 us; speedup vs baseline: 2.5583x; 2.5583x over previous
//
#include <hip/hip_runtime.h>
#include <math.h>

#define NDIS 8192
#define NMIR 16384
#define NTOT 24576
#define DIMD 256
#define BPAIR 65536
#define KSEL 50
#define EPSF 1e-8f

#define RB 64    // rows per block (4 waves x 16 rows)
#define CBC 64   // cols per chunk
#define SST 68   // sims LDS row stride (floats)

typedef __attribute__((ext_vector_type(8))) short bf16x8;
typedef __attribute__((ext_vector_type(4))) float f32x4;

__device__ __forceinline__ float wredsum(float v) {
#pragma unroll
  for (int off = 1; off < 64; off <<= 1) v += __shfl_xor(v, off, 64);
  return v;
}

__device__ __forceinline__ float softplusf(float x) {
  return fmaxf(x, 0.0f) + log1pf(expf(-fabsf(x)));
}

__device__ __forceinline__ float dot4f(const float4 a, const float4 b) {
  return a.x * b.x + a.y * b.y + a.z * b.z + a.w * b.w;
}

__device__ __forceinline__ unsigned short f2bf(float f) {
  unsigned u = __float_as_uint(f);
  unsigned r = (u + 0x7fffu + ((u >> 16) & 1u)) >> 16;
  return (unsigned short)r;
}

// ---------- Kernel 0: fp32 -> bf16 conversion of emb ----------
__global__ __launch_bounds__(256) void convert_kernel(
    const float* __restrict__ in, unsigned short* __restrict__ out) {
  const int i = (blockIdx.x * 256 + threadIdx.x) * 4;
  const float4 v = *(const float4*)(in + i);
  ushort4 o;
  o.x = f2bf(v.x); o.y = f2bf(v.y); o.z = f2bf(v.z); o.w = f2bf(v.w);
  *(ushort4*)(out + i) = o;
}

// ---------- Kernel A: pair scores + contrastive loss partials ----------
__global__ __launch_bounds__(256) void pair_kernel(
    const float* __restrict__ h, const float* __restrict__ srci,
    const float* __restrict__ dsti, const int* __restrict__ dis,
    const int* __restrict__ mir, float* __restrict__ scores,
    float* __restrict__ pairpart) {
  const int lane = threadIdx.x & 63;
  const int widx = threadIdx.x >> 6;
  const int gw = blockIdx.x * 4 + widx;  // 4096 waves total
  float lsum = 0.0f;
  for (int b = gw; b < BPAIR; b += 4096) {
    const int d = dis[b];
    const int m = mir[b];
    const float4 a4 = ((const float4*)(h + (size_t)d * DIMD))[lane];
    const float4 m4 = ((const float4*)(h + (size_t)m * DIMD))[lane];
    const float4 s4 = ((const float4*)(srci + (size_t)b * DIMD))[lane];
    const float4 t4 = ((const float4*)(dsti + (size_t)b * DIMD))[lane];
    float aa = dot4f(a4, a4);
    float ss = dot4f(s4, s4);
    float tt = dot4f(t4, t4);
    float as = dot4f(a4, s4);
    float at = dot4f(a4, t4);
    float am = dot4f(a4, m4);
    aa = wredsum(aa); ss = wredsum(ss); tt = wredsum(tt);
    as = wredsum(as); at = wredsum(at); am = wredsum(am);
    const float ra = fmaxf(sqrtf(aa), EPSF);
    const float pos = as / (ra * fmaxf(sqrtf(ss), EPSF));
    const float neg = at / (ra * fmaxf(sqrtf(tt), EPSF));
    lsum += softplusf(neg - pos);
    if (lane == 0) scores[b] = 1.0f / (1.0f + expf(-am));
  }
  __shared__ float wsum[4];
  if (lane == 0) wsum[widx] = lsum;
  __syncthreads();
  if (threadIdx.x == 0)
    pairpart[blockIdx.x] = (wsum[0] + wsum[1]) + (wsum[2] + wsum[3]);
}

// ---------- Kernel B: MFMA sim-GEMM + fused top-50 + neighbor average ----
// Block = 4 waves; wave w owns rows rowbase + w*16 .. +15.
// A fragments (K=256) held in registers; B chunk (64 cols) staged in LDS via
// global_load_lds with inverse-swizzled global source (koff ^= (col&7)<<4)
// so ds_read_b128 B-frag reads are 2-way (free) instead of 16-way conflicted.
__global__ __launch_bounds__(256) void knn_kernel(
    const float* __restrict__ emb, const unsigned short* __restrict__ embb,
    float* __restrict__ upd_d, float* __restrict__ upd_m) {
  __shared__ char lds[CBC * 512 + RB * SST * 4];  // 32KB B + 17KB sims
  float* Ss = (float*)(lds + CBC * 512);

  const int tid = threadIdx.x;
  const int lane = tid & 63;
  const int widx = tid >> 6;

  const int bid = blockIdx.x;
  const int ism = (bid < (NMIR / RB)) ? 1 : 0;  // mirna blocks first (longer)
  const int lb = ism ? bid : bid - (NMIR / RB);
  const int N = ism ? NMIR : NDIS;
  const size_t goff = ism ? (size_t)NDIS * DIMD : 0;
  const float* featf = emb + goff;
  const unsigned short* featb = embb + goff;
  float* upd = ism ? upd_m : upd_d;

  const int rowbase = lb * RB;

  // load A fragments: row = rowbase + widx*16 + (lane&15), k-groups of 8
  bf16x8 afr[8];
  {
    const int arow = rowbase + widx * 16 + (lane & 15);
    const char* abase =
        (const char*)featb + (size_t)arow * 512 + ((lane >> 4) * 16);
#pragma unroll
    for (int kk = 0; kk < 8; ++kk)
      afr[kk] = *(const bf16x8*)(abase + (size_t)kk * 64);
  }

  // per-wave distributed top-50: lane k (<50) holds slot k
  float tv[16]; int ti[16]; float thr[16];
#pragma unroll
  for (int q = 0; q < 16; ++q) {
    tv[q] = (lane < KSEL) ? -3.4e38f : 3.4e38f;
    ti[q] = 0;
    thr[q] = -3.4e38f;
  }

  const char* gb = (const char*)featb;
  for (int cb = 0; cb < N; cb += CBC) {
    __syncthreads();  // all waves done with previous chunk's B reads
    // stage B chunk: 64 cols x 512B, linear LDS dest, swizzled global src
#pragma unroll
    for (int it = 0; it < 8; ++it) {
      const int m = widx * 8 + it;
      const int col = m * 2 + (lane >> 5);
      const int q = (lane & 31) * 16;
      const int koff = q ^ ((col & 7) << 4);
      const char* src = gb + (size_t)(cb + col) * 512 + koff;
      __builtin_amdgcn_global_load_lds(
          (const __attribute__((address_space(1))) void*)src,
          (__attribute__((address_space(3))) void*)(lds + m * 1024), 16, 0, 0);
    }
    f32x4 acc[4];
#pragma unroll
    for (int t = 0; t < 4; ++t) acc[t] = (f32x4){0.f, 0.f, 0.f, 0.f};
    __syncthreads();  // B visible (vmcnt drained before barrier)

    // compute: 4 col-tiles x 8 k-steps
#pragma unroll
    for (int t = 0; t < 4; ++t) {
      const int col = t * 16 + (lane & 15);
      const char* bbase = lds + (size_t)col * 512;
      const int xr = (col & 7) << 4;
#pragma unroll
      for (int kk = 0; kk < 8; ++kk) {
        const int koff = (kk * 64 + ((lane >> 4) * 16)) ^ xr;
        const bf16x8 b = *(const bf16x8*)(bbase + koff);
        acc[t] = __builtin_amdgcn_mfma_f32_16x16x32_bf16(afr[kk], b, acc[t],
                                                         0, 0, 0);
      }
    }

    // write sims to per-wave-private LDS rows (no cross-wave dep, no barrier)
#pragma unroll
    for (int t = 0; t < 4; ++t) {
#pragma unroll
      for (int j = 0; j < 4; ++j) {
        const int r = widx * 16 + (lane >> 4) * 4 + j;
        Ss[r * SST + t * 16 + (lane & 15)] = acc[t][j];
      }
    }

    // selection on own 16 rows, 64 cols per ballot
#pragma unroll
    for (int q = 0; q < 16; ++q) {
      const int rowq = rowbase + widx * 16 + q;
      const float v = Ss[(widx * 16 + q) * SST + lane];
      const int gc = cb + lane;
      unsigned long long mask = __ballot((gc != rowq) && (v > thr[q]));
      while (mask) {
        const int src = (int)__builtin_ctzll(mask);
        mask &= (mask - 1);
        const float cv = __shfl(v, src, 64);
        if (cv > thr[q]) {
          float mv = tv[q];
          int ml = lane;
#pragma unroll
          for (int off = 1; off < 64; off <<= 1) {
            const float ov = __shfl_xor(mv, off, 64);
            const int ol = __shfl_xor(ml, off, 64);
            if (ov < mv || (ov == mv && ol < ml)) { mv = ov; ml = ol; }
          }
          if (cv > mv && lane == ml) {
            tv[q] = cv;
            ti[q] = cb + src;
          }
          thr[q] = mv;  // min before replacement: conservative
        }
      }
    }
  }

  // gather the 50 neighbors (fp32 originals) and average
#pragma unroll
  for (int q = 0; q < 16; ++q) {
    const int grow = rowbase + widx * 16 + q;
    float ax = 0.f, ay = 0.f, az = 0.f, aw = 0.f;
    for (int t = 0; t < KSEL; ++t) {
      const int j = __shfl(ti[q], t, 64);
      const float4 f4 = ((const float4*)(featf + (size_t)j * DIMD))[lane];
      ax += f4.x; ay += f4.y; az += f4.z; aw += f4.w;
    }
    const float inv = 1.0f / (float)KSEL;
    float4 o;
    o.x = ax * inv; o.y = ay * inv; o.z = az * inv; o.w = aw * inv;
    ((float4*)(upd + (size_t)grow * DIMD))[lane] = o;
  }
}

// ---------- Kernel C1: per-column partial sums for center ----------
__global__ __launch_bounds__(256) void center_partial(
    const float* __restrict__ upd, const int N, float* __restrict__ part) {
  const int c = threadIdx.x;
  const int rows_per = N >> 7;  // grid = 128 blocks
  const int r0 = blockIdx.x * rows_per;
  float s = 0.0f;
  for (int i = 0; i < rows_per; ++i) s += upd[(size_t)(r0 + i) * DIMD + c];
  part[blockIdx.x * DIMD + c] = s;
}

// ---------- Kernel C2: finalize center + its norm ----------
__global__ __launch_bounds__(256) void center_final(
    const float* __restrict__ part, const int N, float* __restrict__ center,
    float* __restrict__ cnorm) {
  const int c = threadIdx.x;
  float s = 0.0f;
  for (int b = 0; b < 128; ++b) s += part[b * DIMD + c];
  s /= (float)N;
  center[c] = s;
  __shared__ float red[256];
  red[c] = s * s;
  __syncthreads();
  for (int off = 128; off > 0; off >>= 1) {
    if (c < off) red[c] += red[c + off];
    __syncthreads();
  }
  if (c == 0) cnorm[0] = sqrtf(red[0]);
}

// ---------- Kernel D: per-row cos vs both centers + softplus partials ----
__global__ __launch_bounds__(256) void knn_loss(
    const float* __restrict__ upd, const int N,
    const float* __restrict__ centers, const float* __restrict__ cnorms,
    const int group, float* __restrict__ part) {
  const int lane = threadIdx.x & 63;
  const int widx = threadIdx.x >> 6;
  const int gw = blockIdx.x * 4 + widx;  // 1024 waves
  const float4 ca = ((const float4*)centers)[lane];
  const float4 cbv = ((const float4*)(centers + DIMD))[lane];
  const float na = fmaxf(cnorms[0], EPSF);
  const float nb = fmaxf(cnorms[1], EPSF);
  float lsum = 0.0f;
  for (int r = gw; r < N; r += 1024) {
    const float4 u = ((const float4*)(upd + (size_t)r * DIMD))[lane];
    float uu = dot4f(u, u);
    float uca = dot4f(u, ca);
    float ucb = dot4f(u, cbv);
    uu = wredsum(uu); uca = wredsum(uca); ucb = wredsum(ucb);
    const float nu = fmaxf(sqrtf(uu), EPSF);
    const float sa = uca / (nu * na);
    const float sb = ucb / (nu * nb);
    const float x = (group == 0) ? (sb - sa) : (sa - sb);
    lsum += softplusf(x);
  }
  __shared__ float wsum[4];
  if (lane == 0) wsum[widx] = lsum;
  __syncthreads();
  if (threadIdx.x == 0)
    part[blockIdx.x] = (wsum[0] + wsum[1]) + (wsum[2] + wsum[3]);
}

// ---------- Kernel E: final scalar reductions ----------
__global__ __launch_bounds__(256) void finalize_kernel(
    const float* __restrict__ pairpart, const float* __restrict__ lpa,
    const float* __restrict__ lpb, float* __restrict__ out) {
  __shared__ float red[256];
  const int t = threadIdx.x;

  float s = 0.0f;
  for (int i = t; i < 1024; i += 256) s += pairpart[i];
  red[t] = s;
  __syncthreads();
  for (int off = 128; off > 0; off >>= 1) {
    if (t < off) red[t] += red[t + off];
    __syncthreads();
  }
  const float pairsum = red[0];
  __syncthreads();

  red[t] = lpa[t];
  __syncthreads();
  for (int off = 128; off > 0; off >>= 1) {
    if (t < off) red[t] += red[t + off];
    __syncthreads();
  }
  const float la = red[0];
  __syncthreads();

  red[t] = lpb[t];
  __syncthreads();
  for (int off = 128; off > 0; off >>= 1) {
    if (t < off) red[t] += red[t + off];
    __syncthreads();
  }
  const float lb = red[0];

  if (t == 0) {
    out[BPAIR] = pairsum / (float)BPAIR;
    out[BPAIR + 1] = 0.5f * (la / (float)NDIS + lb / (float)NMIR);
  }
}

extern "C" void kernel_launch(void* const* d_in, const int* in_sizes, int n_in,
                              void* d_out, int out_size, void* d_ws,
                              size_t ws_size, hipStream_t stream) {
  const float* h = (const float*)d_in[0];
  const float* emb = (const float*)d_in[1];
  const float* srci = (const float*)d_in[2];
  const float* dsti = (const float*)d_in[3];
  const int* dis = (const int*)d_in[4];
  const int* mir = (const int*)d_in[5];
  float* out = (float*)d_out;

  float* W = (float*)d_ws;
  float* upd_d = W;                                   // 8192*256 f32
  float* upd_m = upd_d + (size_t)NDIS * DIMD;         // 16384*256 f32
  float* pairpart = upd_m + (size_t)NMIR * DIMD;      // 1024
  float* cpart_d = pairpart + 1024;                   // 128*256
  float* cpart_m = cpart_d + 32768;                   // 128*256
  float* centers = cpart_m + 32768;                   // 512 (d then m)
  float* cnorms = centers + 512;                      // 2 (pad 64)
  float* lpa = cnorms + 64;                           // 256
  float* lpb = lpa + 256;                             // 256
  unsigned short* embb = (unsigned short*)(lpb + 256);  // 24576*256 bf16

  convert_kernel<<<(NTOT * DIMD) / 1024, 256, 0, stream>>>(emb, embb);
  pair_kernel<<<1024, 256, 0, stream>>>(h, srci, dsti, dis, mir, out, pairpart);
  knn_kernel<<<(NMIR / RB) + (NDIS / RB), 256, 0, stream>>>(emb, embb, upd_d,
                                                            upd_m);
  center_partial<<<128, 256, 0, stream>>>(upd_d, NDIS, cpart_d);
  center_partial<<<128, 256, 0, stream>>>(upd_m, NMIR, cpart_m);
  center_final<<<1, 256, 0, stream>>>(cpart_d, NDIS, centers, cnorms);
  center_final<<<1, 256, 0, stream>>>(cpart_m, NMIR, centers + DIMD,
                                      cnorms + 1);
  knn_loss<<<256, 256, 0, stream>>>(upd_d, NDIS, centers, cnorms, 0, lpa);
  knn_loss<<<256, 256, 0, stream>>>(upd_m, NMIR, centers, cnorms, 1, lpb);
  finalize_kernel<<<1, 256, 0, stream>>>(pairpart, lpa, lpb, out);
}

// Round 3
// 1076.795 us; speedup vs baseline: 11.0590x; 4.3228x over previous
//
#include <hip/hip_runtime.h>
#include <math.h>

#define NDIS 8192
#define NMIR 16384
#define NTOT 24576
#define DIMD 256
#define BPAIR 65536
#define KSEL 50
#define EPSF 1e-8f

#define SST 68       // sims LDS row stride (floats)
#define STRIPW 8192  // columns per strip (mirna: 2 strips, disease: 1)

typedef __attribute__((ext_vector_type(8))) short bf16x8;
typedef __attribute__((ext_vector_type(4))) float f32x4;
typedef unsigned long long ull;

__device__ __forceinline__ float wredsum(float v) {
#pragma unroll
  for (int off = 1; off < 64; off <<= 1) v += __shfl_xor(v, off, 64);
  return v;
}

__device__ __forceinline__ float softplusf(float x) {
  return fmaxf(x, 0.0f) + log1pf(expf(-fabsf(x)));
}

__device__ __forceinline__ float dot4f(const float4 a, const float4 b) {
  return a.x * b.x + a.y * b.y + a.z * b.z + a.w * b.w;
}

__device__ __forceinline__ unsigned short f2bf(float f) {
  unsigned u = __float_as_uint(f);
  unsigned r = (u + 0x7fffu + ((u >> 16) & 1u)) >> 16;
  return (unsigned short)r;
}

// monotone float <-> ordered-uint maps
__device__ __forceinline__ unsigned ordu(float f) {
  unsigned u = __float_as_uint(f);
  return (u & 0x80000000u) ? ~u : (u | 0x80000000u);
}
__device__ __forceinline__ float unord(unsigned x) {
  unsigned u = (x & 0x80000000u) ? (x & 0x7fffffffu) : ~x;
  return __uint_as_float(u);
}

// ---------- Kernel 0: fp32 -> bf16 conversion of emb ----------
__global__ __launch_bounds__(256) void convert_kernel(
    const float* __restrict__ in, unsigned short* __restrict__ out) {
  const int i = (blockIdx.x * 256 + threadIdx.x) * 4;
  const float4 v = *(const float4*)(in + i);
  ushort4 o;
  o.x = f2bf(v.x); o.y = f2bf(v.y); o.z = f2bf(v.z); o.w = f2bf(v.w);
  *(ushort4*)(out + i) = o;
}

// ---------- Kernel A: pair scores + contrastive loss partials ----------
__global__ __launch_bounds__(256) void pair_kernel(
    const float* __restrict__ h, const float* __restrict__ srci,
    const float* __restrict__ dsti, const int* __restrict__ dis,
    const int* __restrict__ mir, float* __restrict__ scores,
    float* __restrict__ pairpart) {
  const int lane = threadIdx.x & 63;
  const int widx = threadIdx.x >> 6;
  const int gw = blockIdx.x * 4 + widx;
  float lsum = 0.0f;
  for (int b = gw; b < BPAIR; b += 4096) {
    const int d = dis[b];
    const int m = mir[b];
    const float4 a4 = ((const float4*)(h + (size_t)d * DIMD))[lane];
    const float4 m4 = ((const float4*)(h + (size_t)m * DIMD))[lane];
    const float4 s4 = ((const float4*)(srci + (size_t)b * DIMD))[lane];
    const float4 t4 = ((const float4*)(dsti + (size_t)b * DIMD))[lane];
    float aa = dot4f(a4, a4);
    float ss = dot4f(s4, s4);
    float tt = dot4f(t4, t4);
    float as = dot4f(a4, s4);
    float at = dot4f(a4, t4);
    float am = dot4f(a4, m4);
    aa = wredsum(aa); ss = wredsum(ss); tt = wredsum(tt);
    as = wredsum(as); at = wredsum(at); am = wredsum(am);
    const float ra = fmaxf(sqrtf(aa), EPSF);
    const float pos = as / (ra * fmaxf(sqrtf(ss), EPSF));
    const float neg = at / (ra * fmaxf(sqrtf(tt), EPSF));
    lsum += softplusf(neg - pos);
    if (lane == 0) scores[b] = 1.0f / (1.0f + expf(-am));
  }
  __shared__ float wsum[4];
  if (lane == 0) wsum[widx] = lsum;
  __syncthreads();
  if (threadIdx.x == 0)
    pairpart[blockIdx.x] = (wsum[0] + wsum[1]) + (wsum[2] + wsum[3]);
}

// ---------- Kernel B: MFMA sim-GEMM + append-buffer top-k candidates ----
// Grid: 640 blocks. bid<512: mirna (strip = bid>>8, rowblock = bid&255);
// else disease (strip 0, rowblock = bid-512). Each block: 64 rows x 8192 cols.
// Per wave: 16 rows. Selection: per-row register candidate buffer C=128
// (2 lane-planes), batched ds_permute appends, threshold compaction on
// overflow (ordered-uint bisect to 50<=count<=64; exact: only entries with
// >=50 better in-strip survivors are dropped).
__global__ __launch_bounds__(256, 3) void knn_kernel(
    const unsigned short* __restrict__ embb, int2* __restrict__ part_d,
    int2* __restrict__ part_m) {
  __shared__ char lds[64 * 512 + 64 * SST * 4];  // 32KB B + 17.4KB sims
  float* Ss = (float*)(lds + 64 * 512);

  const int tid = threadIdx.x;
  const int lane = tid & 63;
  const int widx = tid >> 6;

  const int bid = blockIdx.x;
  const bool ism = bid < 512;
  const int strip = ism ? (bid >> 8) : 0;
  const int rb = ism ? (bid & 255) : (bid - 512);
  const int S = ism ? 2 : 1;
  const unsigned short* featb = embb + (ism ? (size_t)NDIS * DIMD : 0);
  int2* part = ism ? part_m : part_d;

  const int rowbase = rb * 64;
  const int colstart = strip * STRIPW;
  const char* gb = (const char*)featb;

  // A fragments: row = rowbase + widx*16 + (lane&15), k in groups of 32
  bf16x8 afr[8];
  {
    const int arow = rowbase + widx * 16 + (lane & 15);
    const char* abase =
        (const char*)featb + (size_t)arow * 512 + ((lane >> 4) * 16);
#pragma unroll
    for (int kk = 0; kk < 8; ++kk)
      afr[kk] = *(const bf16x8*)(abase + (size_t)kk * 64);
  }

  // selection state: C=128 buffer as two lane-planes
  float bufv0[16], bufv1[16], thr[16];
  int bufi0[16], bufi1[16], cnt[16];
#pragma unroll
  for (int q = 0; q < 16; ++q) {
    bufv0[q] = -3.4e38f; bufv1[q] = -3.4e38f;
    bufi0[q] = 0; bufi1[q] = 0;
    thr[q] = -3.4e38f; cnt[q] = 0;
  }

  // threshold compaction: bisect tau (ordered uints) to 50<=count<=64,
  // drop entries <= tau, repack survivors to slot prefix via ds_permute.
  auto compact = [&](float& bv0, float& bv1, int& bi0, int& bi1, int& cq,
                     float& tq) {
    unsigned lo = ordu(tq);
    unsigned hi = ordu(3.4e38f);
    const unsigned ov0 = ordu(bv0), ov1 = ordu(bv1);
    const bool va0 = lane < cq;
    const bool va1 = (lane + 64) < cq;
    int cn = cq;
    for (int it = 0; it < 24; ++it) {
      if (cn <= 64) break;
      const unsigned mid = lo + ((hi - lo) >> 1);
      const int c = __popcll(__ballot(va0 && (ov0 > mid))) +
                    __popcll(__ballot(va1 && (ov1 > mid)));
      if (c >= KSEL) { lo = mid; cn = c; } else { hi = mid; }
    }
    const bool s0 = va0 && (ov0 > lo);
    const bool s1 = va1 && (ov1 > lo);
    const ull m0 = __ballot(s0), m1 = __ballot(s1);
    const int c0 = __popcll(m0), c1 = __popcll(m1);
    const ull bel = (1ull << lane) - 1;
    const int r0 = __popcll(m0 & bel), nr0 = lane - r0;
    const int r1 = __popcll(m1 & bel), nr1 = lane - r1;
    const int dA = (s0 ? r0 : (c0 + nr0)) & 63;
    const int dB = (s1 ? (c0 + r1) : (c0 + c1 + nr1)) & 63;
    const int tvA = __builtin_amdgcn_ds_permute(dA * 4, __float_as_int(bv0));
    const int tiA = __builtin_amdgcn_ds_permute(dA * 4, bi0);
    const int tvB = __builtin_amdgcn_ds_permute(dB * 4, __float_as_int(bv1));
    const int tiB = __builtin_amdgcn_ds_permute(dB * 4, bi1);
    const int R = c0 + c1;
    const bool A0 = lane < c0;
    const bool B0 = (lane >= c0) && (lane < R);
    const bool B1 = ((lane + 64) >= c0) && ((lane + 64) < R);
    bv0 = A0 ? __int_as_float(tvA) : (B0 ? __int_as_float(tvB) : bv0);
    bi0 = A0 ? tiA : (B0 ? tiB : bi0);
    bv1 = B1 ? __int_as_float(tvB) : bv1;
    bi1 = B1 ? tiB : bi1;
    cq = R;
    tq = unord(lo);
  };

  // batched append of this chunk's passing candidates (bijective lane push)
  auto append = [&](float v, int gc, ull mask, int nc, float& bv0, float& bv1,
                    int& bi0, int& bi1, int& cq) {
    const ull bel = (1ull << lane) - 1;
    const bool pas = (mask >> lane) & 1ull;
    const int rank = __popcll(mask & bel);
    const int nrank = lane - rank;
    const int slot = pas ? (cq + rank) : (cq + nc + nrank);
    const int pv =
        __builtin_amdgcn_ds_permute((slot & 63) * 4, __float_as_int(v));
    const int pi = __builtin_amdgcn_ds_permute((slot & 63) * 4, gc);
    const bool t0 = (lane >= cq) && (lane < cq + nc);
    const bool t1 = ((lane + 64) >= cq) && ((lane + 64) < cq + nc);
    bv0 = t0 ? __int_as_float(pv) : bv0;
    bi0 = t0 ? pi : bi0;
    bv1 = t1 ? __int_as_float(pv) : bv1;
    bi1 = t1 ? pi : bi1;
    cq += nc;
  };

  for (int cb0 = 0; cb0 < STRIPW; cb0 += 64) {
    __syncthreads();  // all waves done with previous chunk's B reads
    // stage B chunk: 64 cols x 512B, linear LDS dest, swizzled global src
#pragma unroll
    for (int it = 0; it < 8; ++it) {
      const int m = widx * 8 + it;
      const int col = m * 2 + (lane >> 5);
      const int qq = (lane & 31) * 16;
      const int koff = qq ^ ((col & 7) << 4);
      const char* src = gb + (size_t)(colstart + cb0 + col) * 512 + koff;
      __builtin_amdgcn_global_load_lds(
          (const __attribute__((address_space(1))) void*)src,
          (__attribute__((address_space(3))) void*)(lds + m * 1024), 16, 0, 0);
    }
    f32x4 acc[4];
#pragma unroll
    for (int t = 0; t < 4; ++t) acc[t] = (f32x4){0.f, 0.f, 0.f, 0.f};
    __syncthreads();  // B visible

#pragma unroll
    for (int t = 0; t < 4; ++t) {
      const int col = t * 16 + (lane & 15);
      const char* bbase = lds + (size_t)col * 512;
      const int xr = (col & 7) << 4;
#pragma unroll
      for (int kk = 0; kk < 8; ++kk) {
        const int koff = (kk * 64 + ((lane >> 4) * 16)) ^ xr;
        const bf16x8 b = *(const bf16x8*)(bbase + koff);
        acc[t] = __builtin_amdgcn_mfma_f32_16x16x32_bf16(afr[kk], b, acc[t],
                                                         0, 0, 0);
      }
    }

    // sims to per-wave-private LDS rows (wave-local, no barrier needed)
#pragma unroll
    for (int t = 0; t < 4; ++t) {
#pragma unroll
      for (int j = 0; j < 4; ++j) {
        const int r = widx * 16 + (lane >> 4) * 4 + j;
        Ss[r * SST + t * 16 + (lane & 15)] = acc[t][j];
      }
    }

    // scan + append per row
#pragma unroll
    for (int q = 0; q < 16; ++q) {
      const int wrow = widx * 16 + q;
      const int growq = rowbase + wrow;
      const float v = Ss[wrow * SST + lane];
      const int gc = colstart + cb0 + lane;
      bool pas = (v > thr[q]) && (gc != growq);
      ull mask = __ballot(pas);
      int nc = __popcll(mask);
      if (nc) {  // wave-uniform
        if (cnt[q] + nc > 128) {  // wave-uniform, rare
          compact(bufv0[q], bufv1[q], bufi0[q], bufi1[q], cnt[q], thr[q]);
          pas = pas && (v > thr[q]);
          mask = __ballot(pas);
          nc = __popcll(mask);
          if (cnt[q] + nc > 128) {  // tie-cluster safety (prob ~0)
            const ull bel = (1ull << lane) - 1;
            pas = pas && (__popcll(mask & bel) < (128 - cnt[q]));
            mask = __ballot(pas);
            nc = __popcll(mask);
          }
        }
        if (nc)
          append(v, gc, mask, nc, bufv0[q], bufv1[q], bufi0[q], bufi1[q],
                 cnt[q]);
      }
    }
  }

  // final: ensure <=64 entries (plane 0), dump 64 slots per row/strip
#pragma unroll
  for (int q = 0; q < 16; ++q) {
    if (cnt[q] > 64)
      compact(bufv0[q], bufv1[q], bufi0[q], bufi1[q], cnt[q], thr[q]);
    const int growq = rowbase + widx * 16 + q;
    int2 e;
    e.x = (lane < cnt[q]) ? __float_as_int(bufv0[q]) : (int)0xFF800000u;
    e.y = bufi0[q];
    part[((size_t)growq * S + strip) * 64 + lane] = e;
  }
}

// ---------- Kernel B2: merge strip candidates, exact top-50, gather ----
// One wave per row; bitonic-128 sort (desc) of up to S*64 candidates.
__global__ __launch_bounds__(256) void merge_kernel(
    const float* __restrict__ emb, const int2* __restrict__ part_d,
    const int2* __restrict__ part_m, float* __restrict__ upd_d,
    float* __restrict__ upd_m) {
  const int lane = threadIdx.x & 63;
  const int widx = threadIdx.x >> 6;
  const int grow = blockIdx.x * 4 + widx;
  const bool ism = grow >= NDIS;
  const int row = ism ? (grow - NDIS) : grow;
  const int S = ism ? 2 : 1;
  const int2* pb =
      ism ? (part_m + (size_t)row * 128) : (part_d + (size_t)row * 64);
  const float* femb = emb + (ism ? (size_t)NDIS * DIMD : 0);
  float* upd = ism ? upd_m : upd_d;

  float v[2];
  int id[2];
#pragma unroll
  for (int j = 0; j < 2; ++j) {
    const int e = j * 64 + lane;
    if (e < S * 64) {
      const int2 E = pb[e];
      v[j] = __int_as_float(E.x);
      id[j] = E.y;
    } else {
      v[j] = __int_as_float((int)0xFF800000u);  // -inf
      id[j] = 0;
    }
  }

  // bitonic sort 128 descending, layout f = j*64 + lane
#pragma unroll
  for (int k = 2; k <= 128; k <<= 1) {
#pragma unroll
    for (int d = k >> 1; d >= 1; d >>= 1) {
      if (d == 64) {
        const bool sw = v[1] > v[0];
        const float tv = v[0];
        v[0] = sw ? v[1] : v[0];
        v[1] = sw ? tv : v[1];
        const int ti = id[0];
        id[0] = sw ? id[1] : id[0];
        id[1] = sw ? ti : id[1];
      } else {
#pragma unroll
        for (int j = 0; j < 2; ++j) {
          const int f = j * 64 + lane;
          const bool descd = (f & k) == 0;
          const bool upper = (lane & d) != 0;
          const float pv = __shfl_xor(v[j], d, 64);
          const int pi = __shfl_xor(id[j], d, 64);
          const bool keepmax = (descd != upper);
          const bool take = keepmax ? (pv > v[j]) : (pv < v[j]);
          v[j] = take ? pv : v[j];
          id[j] = take ? pi : id[j];
        }
      }
    }
  }

  // gather top-50 (fp32 originals) and average
  float ax = 0.f, ay = 0.f, az = 0.f, aw = 0.f;
#pragma unroll
  for (int t = 0; t < KSEL; ++t) {
    const int nb = __shfl(id[0], t, 64);
    const float4 f4 = ((const float4*)(femb + (size_t)nb * DIMD))[lane];
    ax += f4.x; ay += f4.y; az += f4.z; aw += f4.w;
  }
  const float inv = 1.0f / (float)KSEL;
  float4 o;
  o.x = ax * inv; o.y = ay * inv; o.z = az * inv; o.w = aw * inv;
  ((float4*)(upd + (size_t)row * DIMD))[lane] = o;
}

// ---------- Kernel C1: per-column partial sums for center ----------
__global__ __launch_bounds__(256) void center_partial(
    const float* __restrict__ upd, const int N, float* __restrict__ part) {
  const int c = threadIdx.x;
  const int rows_per = N >> 7;
  const int r0 = blockIdx.x * rows_per;
  float s = 0.0f;
  for (int i = 0; i < rows_per; ++i) s += upd[(size_t)(r0 + i) * DIMD + c];
  part[blockIdx.x * DIMD + c] = s;
}

// ---------- Kernel C2: finalize center + its norm ----------
__global__ __launch_bounds__(256) void center_final(
    const float* __restrict__ part, const int N, float* __restrict__ center,
    float* __restrict__ cnorm) {
  const int c = threadIdx.x;
  float s = 0.0f;
  for (int b = 0; b < 128; ++b) s += part[b * DIMD + c];
  s /= (float)N;
  center[c] = s;
  __shared__ float red[256];
  red[c] = s * s;
  __syncthreads();
  for (int off = 128; off > 0; off >>= 1) {
    if (c < off) red[c] += red[c + off];
    __syncthreads();
  }
  if (c == 0) cnorm[0] = sqrtf(red[0]);
}

// ---------- Kernel D: per-row cos vs both centers + softplus partials ----
__global__ __launch_bounds__(256) void knn_loss(
    const float* __restrict__ upd, const int N,
    const float* __restrict__ centers, const float* __restrict__ cnorms,
    const int group, float* __restrict__ part) {
  const int lane = threadIdx.x & 63;
  const int widx = threadIdx.x >> 6;
  const int gw = blockIdx.x * 4 + widx;
  const float4 ca = ((const float4*)centers)[lane];
  const float4 cbv = ((const float4*)(centers + DIMD))[lane];
  const float na = fmaxf(cnorms[0], EPSF);
  const float nb = fmaxf(cnorms[1], EPSF);
  float lsum = 0.0f;
  for (int r = gw; r < N; r += 1024) {
    const float4 u = ((const float4*)(upd + (size_t)r * DIMD))[lane];
    float uu = dot4f(u, u);
    float uca = dot4f(u, ca);
    float ucb = dot4f(u, cbv);
    uu = wredsum(uu); uca = wredsum(uca); ucb = wredsum(ucb);
    const float nu = fmaxf(sqrtf(uu), EPSF);
    const float sa = uca / (nu * na);
    const float sb = ucb / (nu * nb);
    const float x = (group == 0) ? (sb - sa) : (sa - sb);
    lsum += softplusf(x);
  }
  __shared__ float wsum[4];
  if (lane == 0) wsum[widx] = lsum;
  __syncthreads();
  if (threadIdx.x == 0)
    part[blockIdx.x] = (wsum[0] + wsum[1]) + (wsum[2] + wsum[3]);
}

// ---------- Kernel E: final scalar reductions ----------
__global__ __launch_bounds__(256) void finalize_kernel(
    const float* __restrict__ pairpart, const float* __restrict__ lpa,
    const float* __restrict__ lpb, float* __restrict__ out) {
  __shared__ float red[256];
  const int t = threadIdx.x;

  float s = 0.0f;
  for (int i = t; i < 1024; i += 256) s += pairpart[i];
  red[t] = s;
  __syncthreads();
  for (int off = 128; off > 0; off >>= 1) {
    if (t < off) red[t] += red[t + off];
    __syncthreads();
  }
  const float pairsum = red[0];
  __syncthreads();

  red[t] = lpa[t];
  __syncthreads();
  for (int off = 128; off > 0; off >>= 1) {
    if (t < off) red[t] += red[t + off];
    __syncthreads();
  }
  const float la = red[0];
  __syncthreads();

  red[t] = lpb[t];
  __syncthreads();
  for (int off = 128; off > 0; off >>= 1) {
    if (t < off) red[t] += red[t + off];
    __syncthreads();
  }
  const float lb = red[0];

  if (t == 0) {
    out[BPAIR] = pairsum / (float)BPAIR;
    out[BPAIR + 1] = 0.5f * (la / (float)NDIS + lb / (float)NMIR);
  }
}

extern "C" void kernel_launch(void* const* d_in, const int* in_sizes, int n_in,
                              void* d_out, int out_size, void* d_ws,
                              size_t ws_size, hipStream_t stream) {
  const float* h = (const float*)d_in[0];
  const float* emb = (const float*)d_in[1];
  const float* srci = (const float*)d_in[2];
  const float* dsti = (const float*)d_in[3];
  const int* dis = (const int*)d_in[4];
  const int* mir = (const int*)d_in[5];
  float* out = (float*)d_out;

  float* W = (float*)d_ws;
  float* upd_d = W;                                    // 8192*256 f32
  float* upd_m = upd_d + (size_t)NDIS * DIMD;          // 16384*256 f32
  float* pairpart = upd_m + (size_t)NMIR * DIMD;       // 1024
  float* cpart_d = pairpart + 1024;                    // 128*256
  float* cpart_m = cpart_d + 32768;                    // 128*256
  float* centers = cpart_m + 32768;                    // 512 (d then m)
  float* cnorms = centers + 512;                       // 2 (pad 64)
  float* lpa = cnorms + 64;                            // 256
  float* lpb = lpa + 256;                              // 256
  unsigned short* embb = (unsigned short*)(lpb + 256); // 24576*256 bf16
  int2* part_d = (int2*)(embb + (size_t)NTOT * DIMD);  // 8192*1*64 int2
  int2* part_m = part_d + (size_t)NDIS * 64;           // 16384*2*64 int2

  convert_kernel<<<(NTOT * DIMD) / 1024, 256, 0, stream>>>(emb, embb);
  pair_kernel<<<1024, 256, 0, stream>>>(h, srci, dsti, dis, mir, out, pairpart);
  knn_kernel<<<640, 256, 0, stream>>>(embb, part_d, part_m);
  merge_kernel<<<NTOT / 4, 256, 0, stream>>>(emb, part_d, part_m, upd_d,
                                             upd_m);
  center_partial<<<128, 256, 0, stream>>>(upd_d, NDIS, cpart_d);
  center_partial<<<128, 256, 0, stream>>>(upd_m, NMIR, cpart_m);
  center_final<<<1, 256, 0, stream>>>(cpart_d, NDIS, centers, cnorms);
  center_final<<<1, 256, 0, stream>>>(cpart_m, NMIR, centers + DIMD,
                                      cnorms + 1);
  knn_loss<<<256, 256, 0, stream>>>(upd_d, NDIS, centers, cnorms, 0, lpa);
  knn_loss<<<256, 256, 0, stream>>>(upd_m, NMIR, centers, cnorms, 1, lpb);
  finalize_kernel<<<1, 256, 0, stream>>>(pairpart, lpa, lpb, out);
}